// Round 12
// baseline (66.769 us; speedup 1.0000x reference)
//
#include <hip/hip_runtime.h>
#include <hip/hip_bf16.h>

// Problem constants: B=8, C=64, C8=8, H=128, W=128
#define BDIM 8
#define CDIM 64
#define C8DIM 8
#define HDIM 128
#define WDIM 128
#define HW (HDIM * WDIM)   // 16384

typedef short bf16x8 __attribute__((ext_vector_type(8)));
typedef float f32x4 __attribute__((ext_vector_type(4)));

// ---------------- bf16 helpers ----------------
__device__ inline unsigned pk_bf16(float a, float b) {
    unsigned ua = (unsigned)__bfloat16_as_ushort(__float2bfloat16(a));
    unsigned ub = (unsigned)__bfloat16_as_ushort(__float2bfloat16(b));
    return ua | (ub << 16);
}
__device__ inline void cvt2(unsigned u, float& lo, float& hi) {
    lo = __uint_as_float(u << 16);
    hi = __uint_as_float(u & 0xffff0000u);
}

// ---------------------------------------------------------------------------
// Kernel 1: fused QKV projection as MFMA GEMM, X/Y staged through LDS.
//   D[o][p] = sum_c Wall[o][c] * X[c][p],  o in [0,80), c in [0,128)
// 1024 blocks x 512 threads (8 waves); block = (b, 128-position tile).
// Staging: 8 coalesced float4 loads/thread -> cvt bf16 -> sXt[pos][cidx]
// (transposed) with XOR swizzle key k(pos) = ((pos&7)^((pos>>2)&7))<<3 on the
// channel index (bits 3-5). B-fragment read = ONE ds_read_b128 per
// (pair,tensor) at [posl][cbase^key] (involution verified: channel cbase+e
// lands at (cbase^key)+e since key doesn't touch bits 0-2).
// LDS 53.6 KB -> 3 blocks/CU x 8 waves = 24 waves/CU.
// C/D layout: col = lane&15 (p), row = (lane>>4)*4 + reg (o) [HW-verified].
// ---------------------------------------------------------------------------
__global__ __launch_bounds__(512, 6) void qkv_kernel(
    const float* __restrict__ x, const float* __restrict__ y,
    const float* __restrict__ Wq, const float* __restrict__ bq,
    const float* __restrict__ Wk, const float* __restrict__ bk,
    const float* __restrict__ Wv, const float* __restrict__ bv,
    uint4* __restrict__ q_pm, uint4* __restrict__ k_pm, uint4* __restrict__ v_pm)
{
    __shared__ ushort sW[80 * 128];    // [o][c] bf16, XOR-swizzled (existing scheme)
    __shared__ ushort sXt[128 * 128];  // [pos][cidx] bf16; cidx<64 = x, >=64 = y
    __shared__ float  sb[80];

    const int t = threadIdx.x;

    const int blk = blockIdx.x;
    const int b   = blk & 7;
    const int p0  = (blk >> 3) << 7;    // position tile base

    const float* xb = x + (size_t)b * CDIM * HW;
    const float* yb = y + (size_t)b * CDIM * HW;

    // ---- stage X/Y tile: 1024 patches of 4ch x 4pos; 2 patches/thread ----
    {
        float4 f[2][4];
        int q4a[2], ci0a[2];
        #pragma unroll
        for (int it = 0; it < 2; it++) {
            int pi  = t + it * 512;          // 0..1023
            int q4  = pi & 31;               // pos/4
            int ci0 = (pi >> 5) * 4;         // cidx base 0..124 (4-row patch)
            q4a[it] = q4; ci0a[it] = ci0;
            const float* src = (ci0 < 64) ? (xb + (size_t)ci0 * HW)
                                          : (yb + (size_t)(ci0 - 64) * HW);
            const float* sp = src + p0 + q4 * 4;
            f[it][0] = *(const float4*)&sp[0 * HW];
            f[it][1] = *(const float4*)&sp[1 * HW];
            f[it][2] = *(const float4*)&sp[2 * HW];
            f[it][3] = *(const float4*)&sp[3 * HW];
        }
        #pragma unroll
        for (int it = 0; it < 2; it++) {
            #pragma unroll
            for (int j = 0; j < 4; j++) {
                int pos  = q4a[it] * 4 + j;
                int key  = (((pos & 7) ^ ((pos >> 2) & 7)) << 3);
                int cidx = ci0a[it] ^ key;   // key hits bits 3-5 only; ci0%4==0 kept
                uint2 w;
                w.x = pk_bf16(((const float*)&f[it][0])[j], ((const float*)&f[it][1])[j]);
                w.y = pk_bf16(((const float*)&f[it][2])[j], ((const float*)&f[it][3])[j]);
                *(uint2*)&sXt[pos * 128 + cidx] = w;
            }
        }
    }

    // ---- stage weights (80x64 uint = 2 bf16 each), existing swizzle ----
    for (int i = t; i < 80 * 64; i += 512) {
        int o  = i >> 6;
        int cp = i & 63;
        int c  = cp * 2;
        float w0, w1;
        if (o < 8) {
            if (c < 64) { w0 = Wq[o * 64 + c]; w1 = Wq[o * 64 + c + 1]; }
            else        { w0 = 0.f; w1 = 0.f; }
        } else if (o < 16) {
            if (c >= 64) { w0 = Wk[(o - 8) * 64 + c - 64]; w1 = Wk[(o - 8) * 64 + c - 63]; }
            else         { w0 = 0.f; w1 = 0.f; }
        } else {
            w0 = Wv[(o - 16) * 128 + c];
            w1 = Wv[(o - 16) * 128 + c + 1];
        }
        ((unsigned*)sW)[o * 64 + (cp ^ ((o & 7) << 2))] = pk_bf16(w0, w1);
    }
    if (t < 80) {
        sb[t] = (t < 8) ? bq[t] : (t < 16) ? bk[t - 8] : bv[t - 16];
    }
    __syncthreads();

    const int wv = t >> 6, ln = t & 63, lg = ln >> 4, li = ln & 15;
    const int posl = wv * 16 + li;          // 0..127 within tile
    const int keyl = (((posl & 7) ^ ((posl >> 2) & 7)) << 3);

    f32x4 acc[5];
    #pragma unroll
    for (int mt = 0; mt < 5; mt++) acc[mt] = (f32x4){0.f, 0.f, 0.f, 0.f};

    #pragma unroll
    for (int pair = 0; pair < 2; pair++) {
        const int cbx = pair * 32 + lg * 8;
        bf16x8 bx = *(const bf16x8*)&sXt[posl * 128 + (cbx ^ keyl)];
        bf16x8 by = *(const bf16x8*)&sXt[posl * 128 + ((64 + cbx) ^ keyl)];

        #pragma unroll
        for (int mt = 0; mt < 5; mt++) {
            const int row = mt * 16 + li;
            const int sw  = ((li & 7) << 3);
            bf16x8 ax = *(const bf16x8*)&sW[row * 128 + (cbx ^ sw)];
            bf16x8 ay = *(const bf16x8*)&sW[row * 128 + ((64 + cbx) ^ sw)];
            acc[mt] = __builtin_amdgcn_mfma_f32_16x16x32_bf16(ax, bx, acc[mt], 0, 0, 0);
            acc[mt] = __builtin_amdgcn_mfma_f32_16x16x32_bf16(ay, by, acc[mt], 0, 0, 0);
        }
    }

    // ---- epilogue: +bias, pack 4 contiguous o, direct store (pos-major) ----
    const size_t gp = (size_t)b * HW + (size_t)(p0 + posl);
    #pragma unroll
    for (int mt = 0; mt < 5; mt++) {
        const int ob = mt * 16 + lg * 4;
        uint2 w;
        w.x = pk_bf16(acc[mt][0] + sb[ob + 0], acc[mt][1] + sb[ob + 1]);
        w.y = pk_bf16(acc[mt][2] + sb[ob + 2], acc[mt][3] + sb[ob + 3]);
        ushort* dst;
        if (ob < 8)       dst = (ushort*)q_pm + gp * 8 + ob;
        else if (ob < 16) dst = (ushort*)k_pm + gp * 8 + (ob - 8);
        else              dst = (ushort*)v_pm + gp * 64 + (ob - 16);
        *(uint2*)dst = w;
    }
}

// ---------------------------------------------------------------------------
// Kernel 2 (column branch): one block per (b, c).  V/P in LDS are XOR-swizzled
// (ushort col ^= ((row&7)<<3)) -> 52 KB LDS -> 3 blocks/CU.  (unchanged)
// ---------------------------------------------------------------------------
__global__ __launch_bounds__(256, 3) void colattn_kernel(
    const uint4* __restrict__ q_pm, const uint4* __restrict__ k_pm,
    const uint4* __restrict__ v_pm,
    ushort* __restrict__ H_t, float* __restrict__ mH_g, float* __restrict__ sH_g)
{
    __shared__ ushort Q_lds[128 * 8];     // [i][ch]
    __shared__ ushort K_lds[128 * 8];     // [j][ch]
    __shared__ ushort V_lds[64 * 128];    // [ch][j], XOR-swizzled
    __shared__ ushort P_lds[128 * 128];   // [i][j], XOR-swizzled; reused for H

    const int blk = blockIdx.x;
    const int b  = blk & 7;
    const int cc = blk >> 3;
    const int t  = threadIdx.x;

    if (t < 128) {
        *(uint4*)&Q_lds[t * 8] = q_pm[(size_t)b * HW + (size_t)t * 128 + cc];
    } else {
        int j = t - 128;
        *(uint4*)&K_lds[j * 8] = k_pm[(size_t)b * HW + (size_t)j * 128 + cc];
    }
    {
        int j = t & 127, h = t >> 7;
        const uint4* vp = v_pm + ((size_t)b * HW + (size_t)j * 128 + cc) * 8 + 4 * h;
        #pragma unroll
        for (int qd = 0; qd < 4; qd++) {
            uint4 vu = vp[qd];
            int ch0 = 32 * h + 8 * qd;     // multiple of 8
            V_lds[(ch0 + 0) * 128 + (j ^ (0 << 3))] = (ushort)(vu.x & 0xffff);
            V_lds[(ch0 + 1) * 128 + (j ^ (1 << 3))] = (ushort)(vu.x >> 16);
            V_lds[(ch0 + 2) * 128 + (j ^ (2 << 3))] = (ushort)(vu.y & 0xffff);
            V_lds[(ch0 + 3) * 128 + (j ^ (3 << 3))] = (ushort)(vu.y >> 16);
            V_lds[(ch0 + 4) * 128 + (j ^ (4 << 3))] = (ushort)(vu.z & 0xffff);
            V_lds[(ch0 + 5) * 128 + (j ^ (5 << 3))] = (ushort)(vu.z >> 16);
            V_lds[(ch0 + 6) * 128 + (j ^ (6 << 3))] = (ushort)(vu.w & 0xffff);
            V_lds[(ch0 + 7) * 128 + (j ^ (7 << 3))] = (ushort)(vu.w >> 16);
        }
    }
    __syncthreads();

    const int wv = t >> 6, ln = t & 63, lg = ln >> 4, li = ln & 15;
    const bf16x8 zf = {0, 0, 0, 0, 0, 0, 0, 0};

    // ---- QK^T ----
    bf16x8 afr[8], bfr[2];
    #pragma unroll
    for (int jt = 0; jt < 8; jt++)
        afr[jt] = (lg == 0) ? *(const bf16x8*)&K_lds[(jt * 16 + li) * 8] : zf;
    #pragma unroll
    for (int it2 = 0; it2 < 2; it2++)
        bfr[it2] = (lg == 0) ? *(const bf16x8*)&Q_lds[((2 * wv + it2) * 16 + li) * 8] : zf;

    f32x4 dfr[2][8];
    #pragma unroll
    for (int a = 0; a < 2; a++)
        #pragma unroll
        for (int jt = 0; jt < 8; jt++) dfr[a][jt] = (f32x4){0.f, 0.f, 0.f, 0.f};

    #pragma unroll
    for (int it2 = 0; it2 < 2; it2++)
        #pragma unroll
        for (int jt = 0; jt < 8; jt++)
            dfr[it2][jt] = __builtin_amdgcn_mfma_f32_16x16x32_bf16(
                afr[jt], bfr[it2], dfr[it2][jt], 0, 0, 0);

    // ---- softmax (unnormalized, diag masked) ----
    #pragma unroll
    for (int it2 = 0; it2 < 2; it2++) {
        const int i = (2 * wv + it2) * 16 + li;
        float m = -1e30f;
        #pragma unroll
        for (int jt = 0; jt < 8; jt++)
            #pragma unroll
            for (int rr = 0; rr < 4; rr++) {
                int j = jt * 16 + lg * 4 + rr;
                float e = dfr[it2][jt][rr];
                if (j == i) e = -1e30f;
                dfr[it2][jt][rr] = e;
                m = fmaxf(m, e);
            }
        m = fmaxf(m, __shfl_xor(m, 16));
        m = fmaxf(m, __shfl_xor(m, 32));
        float s = 0.f;
        #pragma unroll
        for (int jt = 0; jt < 8; jt++)
            #pragma unroll
            for (int rr = 0; rr < 4; rr++) {
                float p = __expf(dfr[it2][jt][rr] - m);
                dfr[it2][jt][rr] = p;
                s += p;
            }
        s += __shfl_xor(s, 16);
        s += __shfl_xor(s, 32);
        const int swz = (i & 7) << 3;
        #pragma unroll
        for (int jt = 0; jt < 8; jt++) {
            uint2 w;
            w.x = pk_bf16(dfr[it2][jt][0], dfr[it2][jt][1]);
            w.y = pk_bf16(dfr[it2][jt][2], dfr[it2][jt][3]);
            *(uint2*)&P_lds[i * 128 + ((jt * 16 + lg * 4) ^ swz)] = w;
        }
        if (lg == 0) {
            mH_g[((size_t)b * 128 + cc) * 128 + i] = m;
            sH_g[((size_t)b * 128 + cc) * 128 + i] = s;
        }
    }
    __syncthreads();

    // ---- PV ----
    f32x4 ofr[8];
    #pragma unroll
    for (int itl = 0; itl < 8; itl++) ofr[itl] = (f32x4){0.f, 0.f, 0.f, 0.f};

    const int vswz = (li & 7) << 3;
    #pragma unroll
    for (int ks = 0; ks < 4; ks++) {
        const int jb = ks * 32 + lg * 8;
        bf16x8 av = *(const bf16x8*)&V_lds[(wv * 16 + li) * 128 + (jb ^ vswz)];
        #pragma unroll
        for (int itl = 0; itl < 8; itl++) {
            bf16x8 bp = *(const bf16x8*)&P_lds[(itl * 16 + li) * 128 + (jb ^ vswz)];
            ofr[itl] = __builtin_amdgcn_mfma_f32_16x16x32_bf16(av, bp, ofr[itl], 0, 0, 0);
        }
    }
    __syncthreads();   // P_lds dead; reuse as H transpose buffer [128][72]

    #pragma unroll
    for (int itl = 0; itl < 8; itl++) {
        const int i = itl * 16 + li;
        uint2 w;
        w.x = pk_bf16(ofr[itl][0], ofr[itl][1]);
        w.y = pk_bf16(ofr[itl][2], ofr[itl][3]);
        *(uint2*)&P_lds[i * 72 + wv * 16 + lg * 4] = w;
    }
    __syncthreads();

    #pragma unroll
    for (int i2 = 0; i2 < 4; i2++) {
        const int f = t + i2 * 256;          // 128 i x 8 chunks
        const int i = f >> 3, cb = (f & 7) * 8;
        *(uint4*)&H_t[(((size_t)b * 128 + i) * 128 + cc) * 64 + cb] =
            *(const uint4*)&P_lds[i * 72 + cb];
    }
}

// ---------------------------------------------------------------------------
// Kernel 3 (row branch + merge): one block per (b, r).  (unchanged)
// ---------------------------------------------------------------------------
__global__ __launch_bounds__(256, 3) void rowattn_kernel(
    const uint4* __restrict__ q_pm, const uint4* __restrict__ k_pm,
    const uint4* __restrict__ v_pm,
    const ushort* __restrict__ H_t, const float* __restrict__ mH_g,
    const float* __restrict__ sH_g,
    const float* __restrict__ x, const float* __restrict__ y,
    const float* __restrict__ gptr, float* __restrict__ out)
{
    __shared__ ushort Q_lds[128 * 8];     // [i][ch]  (i = column index)
    __shared__ ushort K_lds[128 * 8];     // [j][ch]
    __shared__ ushort V_lds[64 * 128];    // [ch][j], XOR-swizzled
    __shared__ ushort P_lds[128 * 128];   // [i][j], XOR-swizzled
    __shared__ float mW_s[128], sW_s[128];

    const int blk = blockIdx.x;
    const int b = blk & 7;
    const int r = blk >> 3;
    const int t = threadIdx.x;

    if (t < 128) {
        *(uint4*)&Q_lds[t * 8] = q_pm[(size_t)b * HW + (size_t)r * 128 + t];
    } else {
        int j = t - 128;
        *(uint4*)&K_lds[j * 8] = k_pm[(size_t)b * HW + (size_t)r * 128 + j];
    }
    {
        int j = t & 127, h = t >> 7;
        const uint4* vp = v_pm + ((size_t)b * HW + (size_t)r * 128 + j) * 8 + 4 * h;
        #pragma unroll
        for (int qd = 0; qd < 4; qd++) {
            uint4 vu = vp[qd];
            int ch0 = 32 * h + 8 * qd;
            V_lds[(ch0 + 0) * 128 + (j ^ (0 << 3))] = (ushort)(vu.x & 0xffff);
            V_lds[(ch0 + 1) * 128 + (j ^ (1 << 3))] = (ushort)(vu.x >> 16);
            V_lds[(ch0 + 2) * 128 + (j ^ (2 << 3))] = (ushort)(vu.y & 0xffff);
            V_lds[(ch0 + 3) * 128 + (j ^ (3 << 3))] = (ushort)(vu.y >> 16);
            V_lds[(ch0 + 4) * 128 + (j ^ (4 << 3))] = (ushort)(vu.z & 0xffff);
            V_lds[(ch0 + 5) * 128 + (j ^ (5 << 3))] = (ushort)(vu.z >> 16);
            V_lds[(ch0 + 6) * 128 + (j ^ (6 << 3))] = (ushort)(vu.w & 0xffff);
            V_lds[(ch0 + 7) * 128 + (j ^ (7 << 3))] = (ushort)(vu.w >> 16);
        }
    }
    __syncthreads();

    const int wv = t >> 6, ln = t & 63, lg = ln >> 4, li = ln & 15;
    const bf16x8 zf = {0, 0, 0, 0, 0, 0, 0, 0};

    bf16x8 afr[8], bfr[2];
    #pragma unroll
    for (int jt = 0; jt < 8; jt++)
        afr[jt] = (lg == 0) ? *(const bf16x8*)&K_lds[(jt * 16 + li) * 8] : zf;
    #pragma unroll
    for (int it2 = 0; it2 < 2; it2++)
        bfr[it2] = (lg == 0) ? *(const bf16x8*)&Q_lds[((2 * wv + it2) * 16 + li) * 8] : zf;

    f32x4 dfr[2][8];
    #pragma unroll
    for (int a = 0; a < 2; a++)
        #pragma unroll
        for (int jt = 0; jt < 8; jt++) dfr[a][jt] = (f32x4){0.f, 0.f, 0.f, 0.f};

    #pragma unroll
    for (int it2 = 0; it2 < 2; it2++)
        #pragma unroll
        for (int jt = 0; jt < 8; jt++)
            dfr[it2][jt] = __builtin_amdgcn_mfma_f32_16x16x32_bf16(
                afr[jt], bfr[it2], dfr[it2][jt], 0, 0, 0);

    #pragma unroll
    for (int it2 = 0; it2 < 2; it2++) {
        const int i = (2 * wv + it2) * 16 + li;
        float m = -1e30f;
        #pragma unroll
        for (int jt = 0; jt < 8; jt++)
            #pragma unroll
            for (int rr = 0; rr < 4; rr++)
                m = fmaxf(m, dfr[it2][jt][rr]);
        m = fmaxf(m, __shfl_xor(m, 16));
        m = fmaxf(m, __shfl_xor(m, 32));
        float s = 0.f;
        #pragma unroll
        for (int jt = 0; jt < 8; jt++)
            #pragma unroll
            for (int rr = 0; rr < 4; rr++) {
                float p = __expf(dfr[it2][jt][rr] - m);
                dfr[it2][jt][rr] = p;
                s += p;
            }
        s += __shfl_xor(s, 16);
        s += __shfl_xor(s, 32);
        const int swz = (i & 7) << 3;
        #pragma unroll
        for (int jt = 0; jt < 8; jt++) {
            uint2 w;
            w.x = pk_bf16(dfr[it2][jt][0], dfr[it2][jt][1]);
            w.y = pk_bf16(dfr[it2][jt][2], dfr[it2][jt][3]);
            *(uint2*)&P_lds[i * 128 + ((jt * 16 + lg * 4) ^ swz)] = w;
        }
        if (lg == 0) {
            mW_s[i] = m;
            sW_s[i] = s;
        }
    }
    __syncthreads();

    f32x4 ofr[8];
    #pragma unroll
    for (int itl = 0; itl < 8; itl++) ofr[itl] = (f32x4){0.f, 0.f, 0.f, 0.f};

    const int vswz = (li & 7) << 3;
    #pragma unroll
    for (int ks = 0; ks < 4; ks++) {
        const int jb = ks * 32 + lg * 8;
        bf16x8 av = *(const bf16x8*)&V_lds[(wv * 16 + li) * 128 + (jb ^ vswz)];
        #pragma unroll
        for (int itl = 0; itl < 8; itl++) {
            bf16x8 bp = *(const bf16x8*)&P_lds[(itl * 16 + li) * 128 + (jb ^ vswz)];
            ofr[itl] = __builtin_amdgcn_mfma_f32_16x16x32_bf16(av, bp, ofr[itl], 0, 0, 0);
        }
    }

    const float gamma = gptr[0];
    #pragma unroll
    for (int itl = 0; itl < 8; itl++) {
        const int i = itl * 16 + li;     // column index of this position
        float mWv = mW_s[i], sWv = sW_s[i];
        float mHv = mH_g[((size_t)b * 128 + i) * 128 + r];
        float sHv = sH_g[((size_t)b * 128 + i) * 128 + r];
        float m  = fmaxf(mHv, mWv);
        float wH = __expf(mHv - m);
        float wW = __expf(mWv - m);
        float invg = gamma / (sHv * wH + sWv * wW);

        uint2 hw = *(const uint2*)&H_t[(((size_t)b * 128 + r) * 128 + i) * 64 + wv * 16 + lg * 4];
        float h[4];
        cvt2(hw.x, h[0], h[1]);
        cvt2(hw.y, h[2], h[3]);

        #pragma unroll
        for (int rr = 0; rr < 4; rr++) {
            const int ch = wv * 16 + lg * 4 + rr;
            size_t o = (((size_t)b * 64 + ch) * 128 + r) * 128 + i;
            out[o] = (h[rr] * wH + ofr[itl][rr] * wW) * invg + x[o] + y[o];
        }
    }
}

// ---------------------------------------------------------------------------
extern "C" void kernel_launch(void* const* d_in, const int* in_sizes, int n_in,
                              void* d_out, int out_size, void* d_ws, size_t ws_size,
                              hipStream_t stream)
{
    const float* x     = (const float*)d_in[0];
    const float* y     = (const float*)d_in[1];
    const float* Wq    = (const float*)d_in[2];
    const float* bq    = (const float*)d_in[3];
    const float* Wk    = (const float*)d_in[4];
    const float* bk    = (const float*)d_in[5];
    const float* Wv    = (const float*)d_in[6];
    const float* bv    = (const float*)d_in[7];
    const float* gamma = (const float*)d_in[8];
    float* out = (float*)d_out;

    // Workspace: q 2MB | k 2MB | v 16MB | H_t 16MB | mH .5MB | sH .5MB
    uint4*  q_pm = (uint4*)d_ws;                        // 131072 uint4
    uint4*  k_pm = q_pm + (size_t)BDIM * HW;            // 131072 uint4
    uint4*  v_pm = k_pm + (size_t)BDIM * HW;            // 1048576 uint4
    ushort* H_t  = (ushort*)(v_pm + (size_t)BDIM * HW * 8);      // 8388608 us
    float*  mH   = (float*)(H_t + (size_t)BDIM * HW * 64);
    float*  sH   = mH + (size_t)BDIM * HW;

    qkv_kernel<<<dim3(BDIM * HW / 128), dim3(512), 0, stream>>>(
        x, y, Wq, bq, Wk, bk, Wv, bv, q_pm, k_pm, v_pm);

    colattn_kernel<<<dim3(BDIM * WDIM), dim3(256), 0, stream>>>(
        q_pm, k_pm, v_pm, H_t, mH, sH);

    rowattn_kernel<<<dim3(BDIM * HDIM), dim3(256), 0, stream>>>(
        q_pm, k_pm, v_pm, H_t, mH, sH, x, y, gamma, out);
}

// Round 13
// 66.693 us; speedup vs baseline: 1.0011x; 1.0011x over previous
//
#include <hip/hip_runtime.h>
#include <hip/hip_bf16.h>

// Problem constants: B=8, C=64, C8=8, H=128, W=128
#define BDIM 8
#define CDIM 64
#define C8DIM 8
#define HDIM 128
#define WDIM 128
#define HW (HDIM * WDIM)   // 16384

typedef short bf16x8 __attribute__((ext_vector_type(8)));
typedef float f32x4 __attribute__((ext_vector_type(4)));

// ---------------- bf16 helpers ----------------
__device__ inline unsigned pk_bf16(float a, float b) {
    unsigned ua = (unsigned)__bfloat16_as_ushort(__float2bfloat16(a));
    unsigned ub = (unsigned)__bfloat16_as_ushort(__float2bfloat16(b));
    return ua | (ub << 16);
}
__device__ inline void cvt2(unsigned u, float& lo, float& hi) {
    lo = __uint_as_float(u << 16);
    hi = __uint_as_float(u & 0xffff0000u);
}

// ---------------------------------------------------------------------------
// Kernel 1: fused QKV projection as MFMA GEMM, X/Y staged through LDS.
// 1024 blocks x 512 threads; block = (b, 128-position tile).
// Order (T14): (a) issue 8 coalesced float4 x/y loads; (b) weight stage
// (hides (a)'s HBM latency); (c) cvt+write x/y tile to sXt (transposed,
// XOR-swizzled); (d) barrier; (e) MFMA with ds_read_b128 B-fragments.
// NO min-waves launch bound (round-12's (512,6) likely spilled).
// Swizzle key k(pos) = ((pos&7)^((pos>>2)&7))<<3 on channel-index bits 3-5;
// involution verified (key never touches bits 0-2, patch base %4==0).
// C/D layout: col = lane&15 (p), row = (lane>>4)*4 + reg (o) [HW-verified].
// ---------------------------------------------------------------------------
__global__ __launch_bounds__(512) void qkv_kernel(
    const float* __restrict__ x, const float* __restrict__ y,
    const float* __restrict__ Wq, const float* __restrict__ bq,
    const float* __restrict__ Wk, const float* __restrict__ bk,
    const float* __restrict__ Wv, const float* __restrict__ bv,
    uint4* __restrict__ q_pm, uint4* __restrict__ k_pm, uint4* __restrict__ v_pm)
{
    __shared__ ushort sW[80 * 128];    // [o][c] bf16, XOR-swizzled
    __shared__ ushort sXt[128 * 128];  // [pos][cidx] bf16; cidx<64 = x, >=64 = y
    __shared__ float  sb[80];

    const int t = threadIdx.x;

    const int blk = blockIdx.x;
    const int b   = blk & 7;
    const int p0  = (blk >> 3) << 7;    // position tile base

    const float* xb = x + (size_t)b * CDIM * HW;
    const float* yb = y + (size_t)b * CDIM * HW;

    // ---- (a) issue X/Y tile loads: 2 patches/thread of 4ch x 4pos ----
    float4 f[2][4];
    int q4a[2], ci0a[2];
    #pragma unroll
    for (int it = 0; it < 2; it++) {
        int pi  = t + it * 512;          // 0..1023
        int q4  = pi & 31;               // pos/4
        int ci0 = (pi >> 5) * 4;         // cidx base 0..124
        q4a[it] = q4; ci0a[it] = ci0;
        const float* src = (ci0 < 64) ? (xb + (size_t)ci0 * HW)
                                      : (yb + (size_t)(ci0 - 64) * HW);
        const float* sp = src + p0 + q4 * 4;
        f[it][0] = *(const float4*)&sp[0 * HW];
        f[it][1] = *(const float4*)&sp[1 * HW];
        f[it][2] = *(const float4*)&sp[2 * HW];
        f[it][3] = *(const float4*)&sp[3 * HW];
    }

    // ---- (b) weight stage (x/y loads in flight above) ----
    for (int i = t; i < 80 * 64; i += 512) {
        int o  = i >> 6;
        int cp = i & 63;
        int c  = cp * 2;
        float w0, w1;
        if (o < 8) {
            if (c < 64) { w0 = Wq[o * 64 + c]; w1 = Wq[o * 64 + c + 1]; }
            else        { w0 = 0.f; w1 = 0.f; }
        } else if (o < 16) {
            if (c >= 64) { w0 = Wk[(o - 8) * 64 + c - 64]; w1 = Wk[(o - 8) * 64 + c - 63]; }
            else         { w0 = 0.f; w1 = 0.f; }
        } else {
            w0 = Wv[(o - 16) * 128 + c];
            w1 = Wv[(o - 16) * 128 + c + 1];
        }
        ((unsigned*)sW)[o * 64 + (cp ^ ((o & 7) << 2))] = pk_bf16(w0, w1);
    }
    if (t < 80) {
        sb[t] = (t < 8) ? bq[t] : (t < 16) ? bk[t - 8] : bv[t - 16];
    }

    // ---- (c) cvt + transposed LDS write of the x/y tile ----
    #pragma unroll
    for (int it = 0; it < 2; it++) {
        #pragma unroll
        for (int j = 0; j < 4; j++) {
            int pos  = q4a[it] * 4 + j;
            int key  = (((pos & 7) ^ ((pos >> 2) & 7)) << 3);
            int cidx = ci0a[it] ^ key;
            uint2 w;
            w.x = pk_bf16(((const float*)&f[it][0])[j], ((const float*)&f[it][1])[j]);
            w.y = pk_bf16(((const float*)&f[it][2])[j], ((const float*)&f[it][3])[j]);
            *(uint2*)&sXt[pos * 128 + cidx] = w;
        }
    }
    __syncthreads();

    const int wv = t >> 6, ln = t & 63, lg = ln >> 4, li = ln & 15;
    const int posl = wv * 16 + li;          // 0..127 within tile
    const int keyl = (((posl & 7) ^ ((posl >> 2) & 7)) << 3);

    f32x4 acc[5];
    #pragma unroll
    for (int mt = 0; mt < 5; mt++) acc[mt] = (f32x4){0.f, 0.f, 0.f, 0.f};

    #pragma unroll
    for (int pair = 0; pair < 2; pair++) {
        const int cbx = pair * 32 + lg * 8;
        bf16x8 bx = *(const bf16x8*)&sXt[posl * 128 + (cbx ^ keyl)];
        bf16x8 by = *(const bf16x8*)&sXt[posl * 128 + ((64 + cbx) ^ keyl)];

        #pragma unroll
        for (int mt = 0; mt < 5; mt++) {
            const int row = mt * 16 + li;
            const int sw  = ((li & 7) << 3);
            bf16x8 ax = *(const bf16x8*)&sW[row * 128 + (cbx ^ sw)];
            bf16x8 ay = *(const bf16x8*)&sW[row * 128 + ((64 + cbx) ^ sw)];
            acc[mt] = __builtin_amdgcn_mfma_f32_16x16x32_bf16(ax, bx, acc[mt], 0, 0, 0);
            acc[mt] = __builtin_amdgcn_mfma_f32_16x16x32_bf16(ay, by, acc[mt], 0, 0, 0);
        }
    }

    // ---- epilogue: +bias, pack 4 contiguous o, direct store (pos-major) ----
    const size_t gp = (size_t)b * HW + (size_t)(p0 + posl);
    #pragma unroll
    for (int mt = 0; mt < 5; mt++) {
        const int ob = mt * 16 + lg * 4;
        uint2 w;
        w.x = pk_bf16(acc[mt][0] + sb[ob + 0], acc[mt][1] + sb[ob + 1]);
        w.y = pk_bf16(acc[mt][2] + sb[ob + 2], acc[mt][3] + sb[ob + 3]);
        ushort* dst;
        if (ob < 8)       dst = (ushort*)q_pm + gp * 8 + ob;
        else if (ob < 16) dst = (ushort*)k_pm + gp * 8 + (ob - 8);
        else              dst = (ushort*)v_pm + gp * 64 + (ob - 16);
        *(uint2*)dst = w;
    }
}

// ---------------------------------------------------------------------------
// Kernel 2 (column branch): one block per (b, c).  V/P in LDS XOR-swizzled
// -> 52 KB LDS -> 3 blocks/CU.  (unchanged from round 11)
// ---------------------------------------------------------------------------
__global__ __launch_bounds__(256, 3) void colattn_kernel(
    const uint4* __restrict__ q_pm, const uint4* __restrict__ k_pm,
    const uint4* __restrict__ v_pm,
    ushort* __restrict__ H_t, float* __restrict__ mH_g, float* __restrict__ sH_g)
{
    __shared__ ushort Q_lds[128 * 8];     // [i][ch]
    __shared__ ushort K_lds[128 * 8];     // [j][ch]
    __shared__ ushort V_lds[64 * 128];    // [ch][j], XOR-swizzled
    __shared__ ushort P_lds[128 * 128];   // [i][j], XOR-swizzled; reused for H

    const int blk = blockIdx.x;
    const int b  = blk & 7;
    const int cc = blk >> 3;
    const int t  = threadIdx.x;

    if (t < 128) {
        *(uint4*)&Q_lds[t * 8] = q_pm[(size_t)b * HW + (size_t)t * 128 + cc];
    } else {
        int j = t - 128;
        *(uint4*)&K_lds[j * 8] = k_pm[(size_t)b * HW + (size_t)j * 128 + cc];
    }
    {
        int j = t & 127, h = t >> 7;
        const uint4* vp = v_pm + ((size_t)b * HW + (size_t)j * 128 + cc) * 8 + 4 * h;
        #pragma unroll
        for (int qd = 0; qd < 4; qd++) {
            uint4 vu = vp[qd];
            int ch0 = 32 * h + 8 * qd;     // multiple of 8
            V_lds[(ch0 + 0) * 128 + (j ^ (0 << 3))] = (ushort)(vu.x & 0xffff);
            V_lds[(ch0 + 1) * 128 + (j ^ (1 << 3))] = (ushort)(vu.x >> 16);
            V_lds[(ch0 + 2) * 128 + (j ^ (2 << 3))] = (ushort)(vu.y & 0xffff);
            V_lds[(ch0 + 3) * 128 + (j ^ (3 << 3))] = (ushort)(vu.y >> 16);
            V_lds[(ch0 + 4) * 128 + (j ^ (4 << 3))] = (ushort)(vu.z & 0xffff);
            V_lds[(ch0 + 5) * 128 + (j ^ (5 << 3))] = (ushort)(vu.z >> 16);
            V_lds[(ch0 + 6) * 128 + (j ^ (6 << 3))] = (ushort)(vu.w & 0xffff);
            V_lds[(ch0 + 7) * 128 + (j ^ (7 << 3))] = (ushort)(vu.w >> 16);
        }
    }
    __syncthreads();

    const int wv = t >> 6, ln = t & 63, lg = ln >> 4, li = ln & 15;
    const bf16x8 zf = {0, 0, 0, 0, 0, 0, 0, 0};

    // ---- QK^T ----
    bf16x8 afr[8], bfr[2];
    #pragma unroll
    for (int jt = 0; jt < 8; jt++)
        afr[jt] = (lg == 0) ? *(const bf16x8*)&K_lds[(jt * 16 + li) * 8] : zf;
    #pragma unroll
    for (int it2 = 0; it2 < 2; it2++)
        bfr[it2] = (lg == 0) ? *(const bf16x8*)&Q_lds[((2 * wv + it2) * 16 + li) * 8] : zf;

    f32x4 dfr[2][8];
    #pragma unroll
    for (int a = 0; a < 2; a++)
        #pragma unroll
        for (int jt = 0; jt < 8; jt++) dfr[a][jt] = (f32x4){0.f, 0.f, 0.f, 0.f};

    #pragma unroll
    for (int it2 = 0; it2 < 2; it2++)
        #pragma unroll
        for (int jt = 0; jt < 8; jt++)
            dfr[it2][jt] = __builtin_amdgcn_mfma_f32_16x16x32_bf16(
                afr[jt], bfr[it2], dfr[it2][jt], 0, 0, 0);

    // ---- softmax (unnormalized, diag masked) ----
    #pragma unroll
    for (int it2 = 0; it2 < 2; it2++) {
        const int i = (2 * wv + it2) * 16 + li;
        float m = -1e30f;
        #pragma unroll
        for (int jt = 0; jt < 8; jt++)
            #pragma unroll
            for (int rr = 0; rr < 4; rr++) {
                int j = jt * 16 + lg * 4 + rr;
                float e = dfr[it2][jt][rr];
                if (j == i) e = -1e30f;
                dfr[it2][jt][rr] = e;
                m = fmaxf(m, e);
            }
        m = fmaxf(m, __shfl_xor(m, 16));
        m = fmaxf(m, __shfl_xor(m, 32));
        float s = 0.f;
        #pragma unroll
        for (int jt = 0; jt < 8; jt++)
            #pragma unroll
            for (int rr = 0; rr < 4; rr++) {
                float p = __expf(dfr[it2][jt][rr] - m);
                dfr[it2][jt][rr] = p;
                s += p;
            }
        s += __shfl_xor(s, 16);
        s += __shfl_xor(s, 32);
        const int swz = (i & 7) << 3;
        #pragma unroll
        for (int jt = 0; jt < 8; jt++) {
            uint2 w;
            w.x = pk_bf16(dfr[it2][jt][0], dfr[it2][jt][1]);
            w.y = pk_bf16(dfr[it2][jt][2], dfr[it2][jt][3]);
            *(uint2*)&P_lds[i * 128 + ((jt * 16 + lg * 4) ^ swz)] = w;
        }
        if (lg == 0) {
            mH_g[((size_t)b * 128 + cc) * 128 + i] = m;
            sH_g[((size_t)b * 128 + cc) * 128 + i] = s;
        }
    }
    __syncthreads();

    // ---- PV ----
    f32x4 ofr[8];
    #pragma unroll
    for (int itl = 0; itl < 8; itl++) ofr[itl] = (f32x4){0.f, 0.f, 0.f, 0.f};

    const int vswz = (li & 7) << 3;
    #pragma unroll
    for (int ks = 0; ks < 4; ks++) {
        const int jb = ks * 32 + lg * 8;
        bf16x8 av = *(const bf16x8*)&V_lds[(wv * 16 + li) * 128 + (jb ^ vswz)];
        #pragma unroll
        for (int itl = 0; itl < 8; itl++) {
            bf16x8 bp = *(const bf16x8*)&P_lds[(itl * 16 + li) * 128 + (jb ^ vswz)];
            ofr[itl] = __builtin_amdgcn_mfma_f32_16x16x32_bf16(av, bp, ofr[itl], 0, 0, 0);
        }
    }
    __syncthreads();   // P_lds dead; reuse as H transpose buffer [128][72]

    #pragma unroll
    for (int itl = 0; itl < 8; itl++) {
        const int i = itl * 16 + li;
        uint2 w;
        w.x = pk_bf16(ofr[itl][0], ofr[itl][1]);
        w.y = pk_bf16(ofr[itl][2], ofr[itl][3]);
        *(uint2*)&P_lds[i * 72 + wv * 16 + lg * 4] = w;
    }
    __syncthreads();

    #pragma unroll
    for (int i2 = 0; i2 < 4; i2++) {
        const int f = t + i2 * 256;          // 128 i x 8 chunks
        const int i = f >> 3, cb = (f & 7) * 8;
        *(uint4*)&H_t[(((size_t)b * 128 + i) * 128 + cc) * 64 + cb] =
            *(const uint4*)&P_lds[i * 72 + cb];
    }
}

// ---------------------------------------------------------------------------
// Kernel 3 (row branch + merge): one block per (b, r).  (unchanged)
// ---------------------------------------------------------------------------
__global__ __launch_bounds__(256, 3) void rowattn_kernel(
    const uint4* __restrict__ q_pm, const uint4* __restrict__ k_pm,
    const uint4* __restrict__ v_pm,
    const ushort* __restrict__ H_t, const float* __restrict__ mH_g,
    const float* __restrict__ sH_g,
    const float* __restrict__ x, const float* __restrict__ y,
    const float* __restrict__ gptr, float* __restrict__ out)
{
    __shared__ ushort Q_lds[128 * 8];     // [i][ch]  (i = column index)
    __shared__ ushort K_lds[128 * 8];     // [j][ch]
    __shared__ ushort V_lds[64 * 128];    // [ch][j], XOR-swizzled
    __shared__ ushort P_lds[128 * 128];   // [i][j], XOR-swizzled
    __shared__ float mW_s[128], sW_s[128];

    const int blk = blockIdx.x;
    const int b = blk & 7;
    const int r = blk >> 3;
    const int t = threadIdx.x;

    if (t < 128) {
        *(uint4*)&Q_lds[t * 8] = q_pm[(size_t)b * HW + (size_t)r * 128 + t];
    } else {
        int j = t - 128;
        *(uint4*)&K_lds[j * 8] = k_pm[(size_t)b * HW + (size_t)r * 128 + j];
    }
    {
        int j = t & 127, h = t >> 7;
        const uint4* vp = v_pm + ((size_t)b * HW + (size_t)r * 128 + j) * 8 + 4 * h;
        #pragma unroll
        for (int qd = 0; qd < 4; qd++) {
            uint4 vu = vp[qd];
            int ch0 = 32 * h + 8 * qd;
            V_lds[(ch0 + 0) * 128 + (j ^ (0 << 3))] = (ushort)(vu.x & 0xffff);
            V_lds[(ch0 + 1) * 128 + (j ^ (1 << 3))] = (ushort)(vu.x >> 16);
            V_lds[(ch0 + 2) * 128 + (j ^ (2 << 3))] = (ushort)(vu.y & 0xffff);
            V_lds[(ch0 + 3) * 128 + (j ^ (3 << 3))] = (ushort)(vu.y >> 16);
            V_lds[(ch0 + 4) * 128 + (j ^ (4 << 3))] = (ushort)(vu.z & 0xffff);
            V_lds[(ch0 + 5) * 128 + (j ^ (5 << 3))] = (ushort)(vu.z >> 16);
            V_lds[(ch0 + 6) * 128 + (j ^ (6 << 3))] = (ushort)(vu.w & 0xffff);
            V_lds[(ch0 + 7) * 128 + (j ^ (7 << 3))] = (ushort)(vu.w >> 16);
        }
    }
    __syncthreads();

    const int wv = t >> 6, ln = t & 63, lg = ln >> 4, li = ln & 15;
    const bf16x8 zf = {0, 0, 0, 0, 0, 0, 0, 0};

    bf16x8 afr[8], bfr[2];
    #pragma unroll
    for (int jt = 0; jt < 8; jt++)
        afr[jt] = (lg == 0) ? *(const bf16x8*)&K_lds[(jt * 16 + li) * 8] : zf;
    #pragma unroll
    for (int it2 = 0; it2 < 2; it2++)
        bfr[it2] = (lg == 0) ? *(const bf16x8*)&Q_lds[((2 * wv + it2) * 16 + li) * 8] : zf;

    f32x4 dfr[2][8];
    #pragma unroll
    for (int a = 0; a < 2; a++)
        #pragma unroll
        for (int jt = 0; jt < 8; jt++) dfr[a][jt] = (f32x4){0.f, 0.f, 0.f, 0.f};

    #pragma unroll
    for (int it2 = 0; it2 < 2; it2++)
        #pragma unroll
        for (int jt = 0; jt < 8; jt++)
            dfr[it2][jt] = __builtin_amdgcn_mfma_f32_16x16x32_bf16(
                afr[jt], bfr[it2], dfr[it2][jt], 0, 0, 0);

    #pragma unroll
    for (int it2 = 0; it2 < 2; it2++) {
        const int i = (2 * wv + it2) * 16 + li;
        float m = -1e30f;
        #pragma unroll
        for (int jt = 0; jt < 8; jt++)
            #pragma unroll
            for (int rr = 0; rr < 4; rr++)
                m = fmaxf(m, dfr[it2][jt][rr]);
        m = fmaxf(m, __shfl_xor(m, 16));
        m = fmaxf(m, __shfl_xor(m, 32));
        float s = 0.f;
        #pragma unroll
        for (int jt = 0; jt < 8; jt++)
            #pragma unroll
            for (int rr = 0; rr < 4; rr++) {
                float p = __expf(dfr[it2][jt][rr] - m);
                dfr[it2][jt][rr] = p;
                s += p;
            }
        s += __shfl_xor(s, 16);
        s += __shfl_xor(s, 32);
        const int swz = (i & 7) << 3;
        #pragma unroll
        for (int jt = 0; jt < 8; jt++) {
            uint2 w;
            w.x = pk_bf16(dfr[it2][jt][0], dfr[it2][jt][1]);
            w.y = pk_bf16(dfr[it2][jt][2], dfr[it2][jt][3]);
            *(uint2*)&P_lds[i * 128 + ((jt * 16 + lg * 4) ^ swz)] = w;
        }
        if (lg == 0) {
            mW_s[i] = m;
            sW_s[i] = s;
        }
    }
    __syncthreads();

    f32x4 ofr[8];
    #pragma unroll
    for (int itl = 0; itl < 8; itl++) ofr[itl] = (f32x4){0.f, 0.f, 0.f, 0.f};

    const int vswz = (li & 7) << 3;
    #pragma unroll
    for (int ks = 0; ks < 4; ks++) {
        const int jb = ks * 32 + lg * 8;
        bf16x8 av = *(const bf16x8*)&V_lds[(wv * 16 + li) * 128 + (jb ^ vswz)];
        #pragma unroll
        for (int itl = 0; itl < 8; itl++) {
            bf16x8 bp = *(const bf16x8*)&P_lds[(itl * 16 + li) * 128 + (jb ^ vswz)];
            ofr[itl] = __builtin_amdgcn_mfma_f32_16x16x32_bf16(av, bp, ofr[itl], 0, 0, 0);
        }
    }

    const float gamma = gptr[0];
    #pragma unroll
    for (int itl = 0; itl < 8; itl++) {
        const int i = itl * 16 + li;     // column index of this position
        float mWv = mW_s[i], sWv = sW_s[i];
        float mHv = mH_g[((size_t)b * 128 + i) * 128 + r];
        float sHv = sH_g[((size_t)b * 128 + i) * 128 + r];
        float m  = fmaxf(mHv, mWv);
        float wH = __expf(mHv - m);
        float wW = __expf(mWv - m);
        float invg = gamma / (sHv * wH + sWv * wW);

        uint2 hw = *(const uint2*)&H_t[(((size_t)b * 128 + r) * 128 + i) * 64 + wv * 16 + lg * 4];
        float h[4];
        cvt2(hw.x, h[0], h[1]);
        cvt2(hw.y, h[2], h[3]);

        #pragma unroll
        for (int rr = 0; rr < 4; rr++) {
            const int ch = wv * 16 + lg * 4 + rr;
            size_t o = (((size_t)b * 64 + ch) * 128 + r) * 128 + i;
            out[o] = (h[rr] * wH + ofr[itl][rr] * wW) * invg + x[o] + y[o];
        }
    }
}

// ---------------------------------------------------------------------------
extern "C" void kernel_launch(void* const* d_in, const int* in_sizes, int n_in,
                              void* d_out, int out_size, void* d_ws, size_t ws_size,
                              hipStream_t stream)
{
    const float* x     = (const float*)d_in[0];
    const float* y     = (const float*)d_in[1];
    const float* Wq    = (const float*)d_in[2];
    const float* bq    = (const float*)d_in[3];
    const float* Wk    = (const float*)d_in[4];
    const float* bk    = (const float*)d_in[5];
    const float* Wv    = (const float*)d_in[6];
    const float* bv    = (const float*)d_in[7];
    const float* gamma = (const float*)d_in[8];
    float* out = (float*)d_out;

    // Workspace: q 2MB | k 2MB | v 16MB | H_t 16MB | mH .5MB | sH .5MB
    uint4*  q_pm = (uint4*)d_ws;                        // 131072 uint4
    uint4*  k_pm = q_pm + (size_t)BDIM * HW;            // 131072 uint4
    uint4*  v_pm = k_pm + (size_t)BDIM * HW;            // 1048576 uint4
    ushort* H_t  = (ushort*)(v_pm + (size_t)BDIM * HW * 8);      // 8388608 us
    float*  mH   = (float*)(H_t + (size_t)BDIM * HW * 64);
    float*  sH   = mH + (size_t)BDIM * HW;

    qkv_kernel<<<dim3(BDIM * HW / 128), dim3(512), 0, stream>>>(
        x, y, Wq, bq, Wk, bk, Wv, bv, q_pm, k_pm, v_pm);

    colattn_kernel<<<dim3(BDIM * WDIM), dim3(256), 0, stream>>>(
        q_pm, k_pm, v_pm, H_t, mH, sH);

    rowattn_kernel<<<dim3(BDIM * HDIM), dim3(256), 0, stream>>>(
        q_pm, k_pm, v_pm, H_t, mH, sH, x, y, gamma, out);
}

// Round 14
// 65.093 us; speedup vs baseline: 1.0257x; 1.0246x over previous
//
#include <hip/hip_runtime.h>
#include <hip/hip_bf16.h>

// Problem constants: B=8, C=64, C8=8, H=128, W=128
#define BDIM 8
#define CDIM 64
#define C8DIM 8
#define HDIM 128
#define WDIM 128
#define HW (HDIM * WDIM)   // 16384

typedef short bf16x8 __attribute__((ext_vector_type(8)));
typedef float f32x4 __attribute__((ext_vector_type(4)));

// ---------------- bf16 helpers ----------------
__device__ inline unsigned pk_bf16(float a, float b) {
    unsigned ua = (unsigned)__bfloat16_as_ushort(__float2bfloat16(a));
    unsigned ub = (unsigned)__bfloat16_as_ushort(__float2bfloat16(b));
    return ua | (ub << 16);
}
__device__ inline void cvt2(unsigned u, float& lo, float& hi) {
    lo = __uint_as_float(u << 16);
    hi = __uint_as_float(u & 0xffff0000u);
}

// ---------------------------------------------------------------------------
// Kernel 1: fused QKV projection as MFMA GEMM, WAVE-PRIVATE LDS staging.
// 1024 blocks x 512 threads (8 waves); block = (b, 128-position tile).
// Weights staged once (the ONLY barrier). Then each wave, barrier-free:
//   issue 4+4 float4 x/y loads (16B/lane coalesced)
//   ds_write x (4KB wave-private) -> 16 ds_read_b32 frags -> 10 MFMA
//   ds_write y (reuse region; DS pipe in-order per wave => safe)
//   -> frags -> 10 MFMA -> direct stores.
// Wave region layout: float idx = ch*16 + (pos ^ key_f), key_f=((ch>>3)&3)*4
// (XOR on 16B blocks; write q-block (q*4)^key_f + (pos&3) == pos^key_f since
// key_f%4==0). Fragment read key_f = lg*4 (since (pair*4+lg)&3 == lg).
// C/D layout: col = lane&15 (p), row = (lane>>4)*4 + reg (o) [HW-verified].
// ---------------------------------------------------------------------------
__global__ __launch_bounds__(512) void qkv_kernel(
    const float* __restrict__ x, const float* __restrict__ y,
    const float* __restrict__ Wq, const float* __restrict__ bq,
    const float* __restrict__ Wk, const float* __restrict__ bk,
    const float* __restrict__ Wv, const float* __restrict__ bv,
    uint4* __restrict__ q_pm, uint4* __restrict__ k_pm, uint4* __restrict__ v_pm)
{
    __shared__ ushort sW[80 * 128];     // 20480 B, XOR-swizzled weights
    __shared__ float  sXw[8 * 1024];    // 8 waves x (64ch x 16pos) fp32 = 32 KB
    __shared__ float  sb[80];

    const int t = threadIdx.x;
    const int blk = blockIdx.x;
    const int b   = blk & 7;
    const int p0  = (blk >> 3) << 7;    // position tile base

    // ---- stage weights (one-time; the only barrier) ----
    for (int i = t; i < 80 * 64; i += 512) {
        int o  = i >> 6;
        int cp = i & 63;
        int c  = cp * 2;
        float w0, w1;
        if (o < 8) {
            if (c < 64) { w0 = Wq[o * 64 + c]; w1 = Wq[o * 64 + c + 1]; }
            else        { w0 = 0.f; w1 = 0.f; }
        } else if (o < 16) {
            if (c >= 64) { w0 = Wk[(o - 8) * 64 + c - 64]; w1 = Wk[(o - 8) * 64 + c - 63]; }
            else         { w0 = 0.f; w1 = 0.f; }
        } else {
            w0 = Wv[(o - 16) * 128 + c];
            w1 = Wv[(o - 16) * 128 + c + 1];
        }
        ((unsigned*)sW)[o * 64 + (cp ^ ((o & 7) << 2))] = pk_bf16(w0, w1);
    }
    if (t < 80) {
        sb[t] = (t < 8) ? bq[t] : (t < 16) ? bk[t - 8] : bv[t - 16];
    }
    __syncthreads();

    const int wv = t >> 6, ln = t & 63, lg = ln >> 4, li = ln & 15;
    const int chL = ln >> 2, qL = ln & 3;         // staging role of this lane
    const int posbase = p0 + wv * 16 + qL * 4;    // 4 positions per lane

    const float* xb = x + (size_t)b * CDIM * HW;
    const float* yb = y + (size_t)b * CDIM * HW;

    // ---- issue x then y loads (y stays in flight during x compute) ----
    float4 fx[4], fy[4];
    #pragma unroll
    for (int j = 0; j < 4; j++) {
        int ch = j * 16 + chL;
        fx[j] = *(const float4*)&xb[(size_t)ch * HW + posbase];
    }
    #pragma unroll
    for (int j = 0; j < 4; j++) {
        int ch = j * 16 + chL;
        fy[j] = *(const float4*)&yb[(size_t)ch * HW + posbase];
    }

    float* wbase = &sXw[wv * 1024];   // this wave's 64ch x 16pos region

    f32x4 acc[5];
    #pragma unroll
    for (int mt = 0; mt < 5; mt++) acc[mt] = (f32x4){0.f, 0.f, 0.f, 0.f};

    const int swl = ((li & 7) << 3);  // weight-read swizzle

    // ================= X half (W cols 0..63) =================
    #pragma unroll
    for (int j = 0; j < 4; j++) {
        int ch    = j * 16 + chL;
        int key_f = ((ch >> 3) & 3) << 2;
        *(float4*)&wbase[ch * 16 + ((qL * 4) ^ key_f)] = fx[j];
    }
    #pragma unroll
    for (int pair = 0; pair < 2; pair++) {
        const int key_f = lg << 2;
        float fr[8];
        #pragma unroll
        for (int e = 0; e < 8; e++)
            fr[e] = wbase[(pair * 32 + lg * 8 + e) * 16 + (li ^ key_f)];
        uint4 u;
        u.x = pk_bf16(fr[0], fr[1]); u.y = pk_bf16(fr[2], fr[3]);
        u.z = pk_bf16(fr[4], fr[5]); u.w = pk_bf16(fr[6], fr[7]);
        bf16x8 bx = *(bf16x8*)&u;
        #pragma unroll
        for (int mt = 0; mt < 5; mt++) {
            const int row = mt * 16 + li;
            bf16x8 ax = *(const bf16x8*)&sW[row * 128 + ((pair * 32 + lg * 8) ^ swl)];
            acc[mt] = __builtin_amdgcn_mfma_f32_16x16x32_bf16(ax, bx, acc[mt], 0, 0, 0);
        }
    }

    // ================= Y half (W cols 64..127), reuse region =================
    #pragma unroll
    for (int j = 0; j < 4; j++) {
        int ch    = j * 16 + chL;
        int key_f = ((ch >> 3) & 3) << 2;
        *(float4*)&wbase[ch * 16 + ((qL * 4) ^ key_f)] = fy[j];
    }
    #pragma unroll
    for (int pair = 0; pair < 2; pair++) {
        const int key_f = lg << 2;
        float fr[8];
        #pragma unroll
        for (int e = 0; e < 8; e++)
            fr[e] = wbase[(pair * 32 + lg * 8 + e) * 16 + (li ^ key_f)];
        uint4 u;
        u.x = pk_bf16(fr[0], fr[1]); u.y = pk_bf16(fr[2], fr[3]);
        u.z = pk_bf16(fr[4], fr[5]); u.w = pk_bf16(fr[6], fr[7]);
        bf16x8 by = *(bf16x8*)&u;
        #pragma unroll
        for (int mt = 0; mt < 5; mt++) {
            const int row = mt * 16 + li;
            bf16x8 ay = *(const bf16x8*)&sW[row * 128 + (((2 + pair) * 32 + lg * 8) ^ swl)];
            acc[mt] = __builtin_amdgcn_mfma_f32_16x16x32_bf16(ay, by, acc[mt], 0, 0, 0);
        }
    }

    // ---- epilogue: +bias, pack 4 contiguous o, direct store (pos-major) ----
    const size_t gp = (size_t)b * HW + (size_t)(p0 + wv * 16 + li);
    #pragma unroll
    for (int mt = 0; mt < 5; mt++) {
        const int ob = mt * 16 + lg * 4;
        uint2 w;
        w.x = pk_bf16(acc[mt][0] + sb[ob + 0], acc[mt][1] + sb[ob + 1]);
        w.y = pk_bf16(acc[mt][2] + sb[ob + 2], acc[mt][3] + sb[ob + 3]);
        ushort* dst;
        if (ob < 8)       dst = (ushort*)q_pm + gp * 8 + ob;
        else if (ob < 16) dst = (ushort*)k_pm + gp * 8 + (ob - 8);
        else              dst = (ushort*)v_pm + gp * 64 + (ob - 16);
        *(uint2*)dst = w;
    }
}

// ---------------------------------------------------------------------------
// Kernel 2 (column branch): one block per (b, c).  V/P in LDS XOR-swizzled
// -> 52 KB LDS -> 3 blocks/CU.  (round-11 exact)
// ---------------------------------------------------------------------------
__global__ __launch_bounds__(256, 3) void colattn_kernel(
    const uint4* __restrict__ q_pm, const uint4* __restrict__ k_pm,
    const uint4* __restrict__ v_pm,
    ushort* __restrict__ H_t, float* __restrict__ mH_g, float* __restrict__ sH_g)
{
    __shared__ ushort Q_lds[128 * 8];     // [i][ch]
    __shared__ ushort K_lds[128 * 8];     // [j][ch]
    __shared__ ushort V_lds[64 * 128];    // [ch][j], XOR-swizzled
    __shared__ ushort P_lds[128 * 128];   // [i][j], XOR-swizzled; reused for H

    const int blk = blockIdx.x;
    const int b  = blk & 7;
    const int cc = blk >> 3;
    const int t  = threadIdx.x;

    if (t < 128) {
        *(uint4*)&Q_lds[t * 8] = q_pm[(size_t)b * HW + (size_t)t * 128 + cc];
    } else {
        int j = t - 128;
        *(uint4*)&K_lds[j * 8] = k_pm[(size_t)b * HW + (size_t)j * 128 + cc];
    }
    {
        int j = t & 127, h = t >> 7;
        const uint4* vp = v_pm + ((size_t)b * HW + (size_t)j * 128 + cc) * 8 + 4 * h;
        #pragma unroll
        for (int qd = 0; qd < 4; qd++) {
            uint4 vu = vp[qd];
            int ch0 = 32 * h + 8 * qd;     // multiple of 8
            V_lds[(ch0 + 0) * 128 + (j ^ (0 << 3))] = (ushort)(vu.x & 0xffff);
            V_lds[(ch0 + 1) * 128 + (j ^ (1 << 3))] = (ushort)(vu.x >> 16);
            V_lds[(ch0 + 2) * 128 + (j ^ (2 << 3))] = (ushort)(vu.y & 0xffff);
            V_lds[(ch0 + 3) * 128 + (j ^ (3 << 3))] = (ushort)(vu.y >> 16);
            V_lds[(ch0 + 4) * 128 + (j ^ (4 << 3))] = (ushort)(vu.z & 0xffff);
            V_lds[(ch0 + 5) * 128 + (j ^ (5 << 3))] = (ushort)(vu.z >> 16);
            V_lds[(ch0 + 6) * 128 + (j ^ (6 << 3))] = (ushort)(vu.w & 0xffff);
            V_lds[(ch0 + 7) * 128 + (j ^ (7 << 3))] = (ushort)(vu.w >> 16);
        }
    }
    __syncthreads();

    const int wv = t >> 6, ln = t & 63, lg = ln >> 4, li = ln & 15;
    const bf16x8 zf = {0, 0, 0, 0, 0, 0, 0, 0};

    // ---- QK^T ----
    bf16x8 afr[8], bfr[2];
    #pragma unroll
    for (int jt = 0; jt < 8; jt++)
        afr[jt] = (lg == 0) ? *(const bf16x8*)&K_lds[(jt * 16 + li) * 8] : zf;
    #pragma unroll
    for (int it2 = 0; it2 < 2; it2++)
        bfr[it2] = (lg == 0) ? *(const bf16x8*)&Q_lds[((2 * wv + it2) * 16 + li) * 8] : zf;

    f32x4 dfr[2][8];
    #pragma unroll
    for (int a = 0; a < 2; a++)
        #pragma unroll
        for (int jt = 0; jt < 8; jt++) dfr[a][jt] = (f32x4){0.f, 0.f, 0.f, 0.f};

    #pragma unroll
    for (int it2 = 0; it2 < 2; it2++)
        #pragma unroll
        for (int jt = 0; jt < 8; jt++)
            dfr[it2][jt] = __builtin_amdgcn_mfma_f32_16x16x32_bf16(
                afr[jt], bfr[it2], dfr[it2][jt], 0, 0, 0);

    // ---- softmax (unnormalized, diag masked) ----
    #pragma unroll
    for (int it2 = 0; it2 < 2; it2++) {
        const int i = (2 * wv + it2) * 16 + li;
        float m = -1e30f;
        #pragma unroll
        for (int jt = 0; jt < 8; jt++)
            #pragma unroll
            for (int rr = 0; rr < 4; rr++) {
                int j = jt * 16 + lg * 4 + rr;
                float e = dfr[it2][jt][rr];
                if (j == i) e = -1e30f;
                dfr[it2][jt][rr] = e;
                m = fmaxf(m, e);
            }
        m = fmaxf(m, __shfl_xor(m, 16));
        m = fmaxf(m, __shfl_xor(m, 32));
        float s = 0.f;
        #pragma unroll
        for (int jt = 0; jt < 8; jt++)
            #pragma unroll
            for (int rr = 0; rr < 4; rr++) {
                float p = __expf(dfr[it2][jt][rr] - m);
                dfr[it2][jt][rr] = p;
                s += p;
            }
        s += __shfl_xor(s, 16);
        s += __shfl_xor(s, 32);
        const int swz = (i & 7) << 3;
        #pragma unroll
        for (int jt = 0; jt < 8; jt++) {
            uint2 w;
            w.x = pk_bf16(dfr[it2][jt][0], dfr[it2][jt][1]);
            w.y = pk_bf16(dfr[it2][jt][2], dfr[it2][jt][3]);
            *(uint2*)&P_lds[i * 128 + ((jt * 16 + lg * 4) ^ swz)] = w;
        }
        if (lg == 0) {
            mH_g[((size_t)b * 128 + cc) * 128 + i] = m;
            sH_g[((size_t)b * 128 + cc) * 128 + i] = s;
        }
    }
    __syncthreads();

    // ---- PV ----
    f32x4 ofr[8];
    #pragma unroll
    for (int itl = 0; itl < 8; itl++) ofr[itl] = (f32x4){0.f, 0.f, 0.f, 0.f};

    const int vswz = (li & 7) << 3;
    #pragma unroll
    for (int ks = 0; ks < 4; ks++) {
        const int jb = ks * 32 + lg * 8;
        bf16x8 av = *(const bf16x8*)&V_lds[(wv * 16 + li) * 128 + (jb ^ vswz)];
        #pragma unroll
        for (int itl = 0; itl < 8; itl++) {
            bf16x8 bp = *(const bf16x8*)&P_lds[(itl * 16 + li) * 128 + (jb ^ vswz)];
            ofr[itl] = __builtin_amdgcn_mfma_f32_16x16x32_bf16(av, bp, ofr[itl], 0, 0, 0);
        }
    }
    __syncthreads();   // P_lds dead; reuse as H transpose buffer [128][72]

    #pragma unroll
    for (int itl = 0; itl < 8; itl++) {
        const int i = itl * 16 + li;
        uint2 w;
        w.x = pk_bf16(ofr[itl][0], ofr[itl][1]);
        w.y = pk_bf16(ofr[itl][2], ofr[itl][3]);
        *(uint2*)&P_lds[i * 72 + wv * 16 + lg * 4] = w;
    }
    __syncthreads();

    #pragma unroll
    for (int i2 = 0; i2 < 4; i2++) {
        const int f = t + i2 * 256;          // 128 i x 8 chunks
        const int i = f >> 3, cb = (f & 7) * 8;
        *(uint4*)&H_t[(((size_t)b * 128 + i) * 128 + cc) * 64 + cb] =
            *(const uint4*)&P_lds[i * 72 + cb];
    }
}

// ---------------------------------------------------------------------------
// Kernel 3 (row branch + merge): one block per (b, r).  (round-11 exact)
// ---------------------------------------------------------------------------
__global__ __launch_bounds__(256, 3) void rowattn_kernel(
    const uint4* __restrict__ q_pm, const uint4* __restrict__ k_pm,
    const uint4* __restrict__ v_pm,
    const ushort* __restrict__ H_t, const float* __restrict__ mH_g,
    const float* __restrict__ sH_g,
    const float* __restrict__ x, const float* __restrict__ y,
    const float* __restrict__ gptr, float* __restrict__ out)
{
    __shared__ ushort Q_lds[128 * 8];     // [i][ch]  (i = column index)
    __shared__ ushort K_lds[128 * 8];     // [j][ch]
    __shared__ ushort V_lds[64 * 128];    // [ch][j], XOR-swizzled
    __shared__ ushort P_lds[128 * 128];   // [i][j], XOR-swizzled
    __shared__ float mW_s[128], sW_s[128];

    const int blk = blockIdx.x;
    const int b = blk & 7;
    const int r = blk >> 3;
    const int t = threadIdx.x;

    if (t < 128) {
        *(uint4*)&Q_lds[t * 8] = q_pm[(size_t)b * HW + (size_t)r * 128 + t];
    } else {
        int j = t - 128;
        *(uint4*)&K_lds[j * 8] = k_pm[(size_t)b * HW + (size_t)r * 128 + j];
    }
    {
        int j = t & 127, h = t >> 7;
        const uint4* vp = v_pm + ((size_t)b * HW + (size_t)r * 128 + j) * 8 + 4 * h;
        #pragma unroll
        for (int qd = 0; qd < 4; qd++) {
            uint4 vu = vp[qd];
            int ch0 = 32 * h + 8 * qd;
            V_lds[(ch0 + 0) * 128 + (j ^ (0 << 3))] = (ushort)(vu.x & 0xffff);
            V_lds[(ch0 + 1) * 128 + (j ^ (1 << 3))] = (ushort)(vu.x >> 16);
            V_lds[(ch0 + 2) * 128 + (j ^ (2 << 3))] = (ushort)(vu.y & 0xffff);
            V_lds[(ch0 + 3) * 128 + (j ^ (3 << 3))] = (ushort)(vu.y >> 16);
            V_lds[(ch0 + 4) * 128 + (j ^ (4 << 3))] = (ushort)(vu.z & 0xffff);
            V_lds[(ch0 + 5) * 128 + (j ^ (5 << 3))] = (ushort)(vu.z >> 16);
            V_lds[(ch0 + 6) * 128 + (j ^ (6 << 3))] = (ushort)(vu.w & 0xffff);
            V_lds[(ch0 + 7) * 128 + (j ^ (7 << 3))] = (ushort)(vu.w >> 16);
        }
    }
    __syncthreads();

    const int wv = t >> 6, ln = t & 63, lg = ln >> 4, li = ln & 15;
    const bf16x8 zf = {0, 0, 0, 0, 0, 0, 0, 0};

    bf16x8 afr[8], bfr[2];
    #pragma unroll
    for (int jt = 0; jt < 8; jt++)
        afr[jt] = (lg == 0) ? *(const bf16x8*)&K_lds[(jt * 16 + li) * 8] : zf;
    #pragma unroll
    for (int it2 = 0; it2 < 2; it2++)
        bfr[it2] = (lg == 0) ? *(const bf16x8*)&Q_lds[((2 * wv + it2) * 16 + li) * 8] : zf;

    f32x4 dfr[2][8];
    #pragma unroll
    for (int a = 0; a < 2; a++)
        #pragma unroll
        for (int jt = 0; jt < 8; jt++) dfr[a][jt] = (f32x4){0.f, 0.f, 0.f, 0.f};

    #pragma unroll
    for (int it2 = 0; it2 < 2; it2++)
        #pragma unroll
        for (int jt = 0; jt < 8; jt++)
            dfr[it2][jt] = __builtin_amdgcn_mfma_f32_16x16x32_bf16(
                afr[jt], bfr[it2], dfr[it2][jt], 0, 0, 0);

    #pragma unroll
    for (int it2 = 0; it2 < 2; it2++) {
        const int i = (2 * wv + it2) * 16 + li;
        float m = -1e30f;
        #pragma unroll
        for (int jt = 0; jt < 8; jt++)
            #pragma unroll
            for (int rr = 0; rr < 4; rr++)
                m = fmaxf(m, dfr[it2][jt][rr]);
        m = fmaxf(m, __shfl_xor(m, 16));
        m = fmaxf(m, __shfl_xor(m, 32));
        float s = 0.f;
        #pragma unroll
        for (int jt = 0; jt < 8; jt++)
            #pragma unroll
            for (int rr = 0; rr < 4; rr++) {
                float p = __expf(dfr[it2][jt][rr] - m);
                dfr[it2][jt][rr] = p;
                s += p;
            }
        s += __shfl_xor(s, 16);
        s += __shfl_xor(s, 32);
        const int swz = (i & 7) << 3;
        #pragma unroll
        for (int jt = 0; jt < 8; jt++) {
            uint2 w;
            w.x = pk_bf16(dfr[it2][jt][0], dfr[it2][jt][1]);
            w.y = pk_bf16(dfr[it2][jt][2], dfr[it2][jt][3]);
            *(uint2*)&P_lds[i * 128 + ((jt * 16 + lg * 4) ^ swz)] = w;
        }
        if (lg == 0) {
            mW_s[i] = m;
            sW_s[i] = s;
        }
    }
    __syncthreads();

    f32x4 ofr[8];
    #pragma unroll
    for (int itl = 0; itl < 8; itl++) ofr[itl] = (f32x4){0.f, 0.f, 0.f, 0.f};

    const int vswz = (li & 7) << 3;
    #pragma unroll
    for (int ks = 0; ks < 4; ks++) {
        const int jb = ks * 32 + lg * 8;
        bf16x8 av = *(const bf16x8*)&V_lds[(wv * 16 + li) * 128 + (jb ^ vswz)];
        #pragma unroll
        for (int itl = 0; itl < 8; itl++) {
            bf16x8 bp = *(const bf16x8*)&P_lds[(itl * 16 + li) * 128 + (jb ^ vswz)];
            ofr[itl] = __builtin_amdgcn_mfma_f32_16x16x32_bf16(av, bp, ofr[itl], 0, 0, 0);
        }
    }

    const float gamma = gptr[0];
    #pragma unroll
    for (int itl = 0; itl < 8; itl++) {
        const int i = itl * 16 + li;     // column index of this position
        float mWv = mW_s[i], sWv = sW_s[i];
        float mHv = mH_g[((size_t)b * 128 + i) * 128 + r];
        float sHv = sH_g[((size_t)b * 128 + i) * 128 + r];
        float m  = fmaxf(mHv, mWv);
        float wH = __expf(mHv - m);
        float wW = __expf(mWv - m);
        float invg = gamma / (sHv * wH + sWv * wW);

        uint2 hw = *(const uint2*)&H_t[(((size_t)b * 128 + r) * 128 + i) * 64 + wv * 16 + lg * 4];
        float h[4];
        cvt2(hw.x, h[0], h[1]);
        cvt2(hw.y, h[2], h[3]);

        #pragma unroll
        for (int rr = 0; rr < 4; rr++) {
            const int ch = wv * 16 + lg * 4 + rr;
            size_t o = (((size_t)b * 64 + ch) * 128 + r) * 128 + i;
            out[o] = (h[rr] * wH + ofr[itl][rr] * wW) * invg + x[o] + y[o];
        }
    }
}

// ---------------------------------------------------------------------------
extern "C" void kernel_launch(void* const* d_in, const int* in_sizes, int n_in,
                              void* d_out, int out_size, void* d_ws, size_t ws_size,
                              hipStream_t stream)
{
    const float* x     = (const float*)d_in[0];
    const float* y     = (const float*)d_in[1];
    const float* Wq    = (const float*)d_in[2];
    const float* bq    = (const float*)d_in[3];
    const float* Wk    = (const float*)d_in[4];
    const float* bk    = (const float*)d_in[5];
    const float* Wv    = (const float*)d_in[6];
    const float* bv    = (const float*)d_in[7];
    const float* gamma = (const float*)d_in[8];
    float* out = (float*)d_out;

    // Workspace: q 2MB | k 2MB | v 16MB | H_t 16MB | mH .5MB | sH .5MB
    uint4*  q_pm = (uint4*)d_ws;                        // 131072 uint4
    uint4*  k_pm = q_pm + (size_t)BDIM * HW;            // 131072 uint4
    uint4*  v_pm = k_pm + (size_t)BDIM * HW;            // 1048576 uint4
    ushort* H_t  = (ushort*)(v_pm + (size_t)BDIM * HW * 8);      // 8388608 us
    float*  mH   = (float*)(H_t + (size_t)BDIM * HW * 64);
    float*  sH   = mH + (size_t)BDIM * HW;

    qkv_kernel<<<dim3(BDIM * HW / 128), dim3(512), 0, stream>>>(
        x, y, Wq, bq, Wk, bk, Wv, bv, q_pm, k_pm, v_pm);

    colattn_kernel<<<dim3(BDIM * WDIM), dim3(256), 0, stream>>>(
        q_pm, k_pm, v_pm, H_t, mH, sH);

    rowattn_kernel<<<dim3(BDIM * HDIM), dim3(256), 0, stream>>>(
        q_pm, k_pm, v_pm, H_t, mH, sH, x, y, gamma, out);
}